// Round 15
// baseline (26.805 us; speedup 1.0000x reference)
//
#include <hip/hip_runtime.h>

typedef __attribute__((ext_vector_type(8))) short bf16x8;
typedef __attribute__((ext_vector_type(4))) float f32x4;
typedef __attribute__((ext_vector_type(2))) float f32x2;

// Native cast -> v_cvt_pk_bf16_f32 on gfx950 (RNE).
__device__ __forceinline__ unsigned short f2bf(float x) {
    union { __bf16 h; unsigned short s; } u;
    u.h = (__bf16)x;
    return u.s;
}

// K1: fused skinny GEMMs (R14 verbatim).
__global__ __launch_bounds__(256) void gemm_fused(
    const float* __restrict__ hs, const float* __restrict__ seqW,
    const float* __restrict__ hidW, const float* __restrict__ cpw,
    unsigned short* __restrict__ E16 /* [2][4096][32] bf16 */)
{
    __shared__ float red[4][16][32];

    const int bid = blockIdx.x;
    const bool hid = bid >= 256;
    const int mt  = hid ? bid - 256 : bid;
    const int tid = threadIdx.x;
    const int wv  = tid >> 6;
    const int l   = tid & 63;
    const int l15 = l & 15;
    const int g   = l >> 4;
    const int m0  = mt * 16;
    const int mrow = m0 + l15;

    const float* __restrict__ W = hid ? hidW : seqW;
    size_t arow;
    if (hid) arow = ((size_t)(mrow >> 10) << 20) + (size_t)(mrow & 1023);
    else     arow = (size_t)mrow << 10;

    f32x4 acc0 = {0.f,0.f,0.f,0.f}, acc1 = {0.f,0.f,0.f,0.f};
    const int kbase = wv * 256;

    #pragma unroll
    for (int ks = 0; ks < 8; ++ks) {
        const int kb = kbase + ks * 32 + g * 8;
        bf16x8 af, bf0, bf1;
        if (hid) {
            const float* pa = hs + arow + (size_t)kb * 1024;
            float a[8];
            #pragma unroll
            for (int j = 0; j < 8; ++j) a[j] = pa[(size_t)j * 1024];
            #pragma unroll
            for (int j = 0; j < 8; ++j) af[j] = (short)f2bf(a[j]);
        } else {
            const f32x4* pa = (const f32x4*)(hs + arow + kb);
            f32x4 a0 = pa[0], a1 = pa[1];
            af[0]=(short)f2bf(a0.x); af[1]=(short)f2bf(a0.y); af[2]=(short)f2bf(a0.z); af[3]=(short)f2bf(a0.w);
            af[4]=(short)f2bf(a1.x); af[5]=(short)f2bf(a1.y); af[6]=(short)f2bf(a1.z); af[7]=(short)f2bf(a1.w);
        }
        {
            const f32x4* pb = (const f32x4*)(W + (size_t)l15 * 1024 + kb);
            f32x4 b0 = pb[0], b1 = pb[1];
            bf0[0]=(short)f2bf(b0.x); bf0[1]=(short)f2bf(b0.y); bf0[2]=(short)f2bf(b0.z); bf0[3]=(short)f2bf(b0.w);
            bf0[4]=(short)f2bf(b1.x); bf0[5]=(short)f2bf(b1.y); bf0[6]=(short)f2bf(b1.z); bf0[7]=(short)f2bf(b1.w);
        }
        {
            const f32x4* pb = (const f32x4*)(W + (size_t)(l15 + 16) * 1024 + kb);
            f32x4 b0 = pb[0], b1 = pb[1];
            bf1[0]=(short)f2bf(b0.x); bf1[1]=(short)f2bf(b0.y); bf1[2]=(short)f2bf(b0.z); bf1[3]=(short)f2bf(b0.w);
            bf1[4]=(short)f2bf(b1.x); bf1[5]=(short)f2bf(b1.y); bf1[6]=(short)f2bf(b1.z); bf1[7]=(short)f2bf(b1.w);
        }
        acc0 = __builtin_amdgcn_mfma_f32_16x16x32_bf16(af, bf0, acc0, 0, 0, 0);
        acc1 = __builtin_amdgcn_mfma_f32_16x16x32_bf16(af, bf1, acc1, 0, 0, 0);
    }

    // C/D layout (m89-verified): col = lane&15, row = (lane>>4)*4 + reg
    #pragma unroll
    for (int r = 0; r < 4; ++r) {
        red[wv][4 * g + r][l15]      = acc0[r];
        red[wv][4 * g + r][l15 + 16] = acc1[r];
    }
    __syncthreads();

    // Sum 4 wave-partials -> fold cpw (seq only) -> bf16 pack -> 4B store.
    const int o = tid * 2;
    const float* rf = &red[0][0][0];
    float vx = rf[o]     + rf[512 + o]     + rf[1024 + o]     + rf[1536 + o];
    float vy = rf[o + 1] + rf[512 + o + 1] + rf[1024 + o + 1] + rf[1536 + o + 1];
    if (!hid) {
        f32x2 w = *(const f32x2*)(cpw + (o & 31));
        vx *= w.x; vy *= w.y;
    }
    unsigned pk = (unsigned)f2bf(vx) | ((unsigned)f2bf(vy) << 16);
    unsigned short* Eo = E16 + (hid ? (size_t)4096 * 32 : 0) + (size_t)m0 * 32 + o;
    *(unsigned*)Eo = pk;
}

// K3: rank-32 GEMM via MFMA (R14 verbatim, nt stores).
// *** MEASUREMENT ROUND: k3 launched TWICE (idempotent) ->
// *** k3+dispatch = dur(R15) - dur(R14) = dur - 22.2us.
__global__ __launch_bounds__(256) void k3(const unsigned short* __restrict__ E16,
                                          float* __restrict__ out)
{
    const int tid = threadIdx.x;
    const int wv  = tid >> 6;
    const int l   = tid & 63;
    const int l15 = l & 15;
    const int g   = l >> 4;
    const int b   = blockIdx.z;
    const int s0  = blockIdx.y * 64 + wv * 16;
    const int h0  = blockIdx.x * 64;

    const unsigned short* As = E16 + ((size_t)(b * 1024 + s0)) * 32;
    const unsigned short* Bh = E16 + (size_t)4096 * 32 + ((size_t)(b * 1024 + h0)) * 32;

    bf16x8 af = *(const bf16x8*)(As + (size_t)l15 * 32 + g * 8);
    bf16x8 bfr[4];
    #pragma unroll
    for (int j = 0; j < 4; ++j)
        bfr[j] = *(const bf16x8*)(Bh + (size_t)(4 * l15 + j) * 32 + g * 8);

    const f32x4 zero = {0.f, 0.f, 0.f, 0.f};
    f32x4 acc[4];
    #pragma unroll
    for (int j = 0; j < 4; ++j)
        acc[j] = __builtin_amdgcn_mfma_f32_16x16x32_bf16(af, bfr[j], zero, 0, 0, 0);

    #pragma unroll
    for (int r = 0; r < 4; ++r) {
        f32x4 v = { acc[0][r], acc[1][r], acc[2][r], acc[3][r] };
        float* orow = out + ((size_t)(b * 1024 + s0 + 4 * g + r)) * 1024 + h0 + 4 * l15;
        __builtin_nontemporal_store(v, (f32x4*)orow);
    }
}

extern "C" void kernel_launch(void* const* d_in, const int* in_sizes, int n_in,
                              void* d_out, int out_size, void* d_ws, size_t ws_size,
                              hipStream_t stream) {
    const float* hs   = (const float*)d_in[0];
    // d_in[1] = all_indices: identically (n/H, n%H) -> computed implicitly
    const float* seqW = (const float*)d_in[2];
    const float* hidW = (const float*)d_in[3];
    const float* cpw  = (const float*)d_in[4];
    float* out = (float*)d_out;

    unsigned short* E16 = (unsigned short*)d_ws;   // [2][4096][32] bf16, 512 KB

    gemm_fused<<<512, 256, 0, stream>>>(hs, seqW, hidW, cpw, E16);
    dim3 grid3(16, 16, 4);
    // MEASUREMENT: double-launch the (idempotent) k3 to expose its duration.
    k3<<<grid3, 256, 0, stream>>>(E16, out);
    k3<<<grid3, 256, 0, stream>>>(E16, out);
}

// Round 16
// 21.242 us; speedup vs baseline: 1.2619x; 1.2619x over previous
//
#include <hip/hip_runtime.h>

typedef __attribute__((ext_vector_type(8))) short bf16x8;
typedef __attribute__((ext_vector_type(4))) float f32x4;
typedef __attribute__((ext_vector_type(2))) float f32x2;
typedef __attribute__((ext_vector_type(4))) short short4v;

// Native cast -> v_cvt_pk_bf16_f32 on gfx950 (RNE).
__device__ __forceinline__ unsigned short f2bf(float x) {
    union { __bf16 h; unsigned short s; } u;
    u.h = (__bf16)x;
    return u.s;
}

// K1: fused skinny GEMMs (R14 structure) + NEW: W staged per-block into LDS in
// MFMA-fragment-ready bf16 layout.
// WHY (R15 measurement): gemm ~10us = 75% of optimizable time, and its B-loads
// (pb = W + l15*1024 + kb) have a 4KB lane stride -> each B-load instruction
// touches ~64 cache lines; ~65K such instrs ~ 7us of L1 transactions. Every
// A-side change was neutral because B was the bottleneck. Staging W into LDS
// fragment-order turns B into 16B/lane ds_read_b128 (off the VMEM pipe).
// Fragment layout: frag(nt,kstep,g,l15) = nt*2048 + kstep*64 + g*16 + l15,
// 16B each, holds W[nt*16+l15][kstep*32+g*8 .. +8] as bf16x8 (same k-slot
// bijection as the A fragment -> k-permutation invariant, numerics unchanged).
// LDS: 64KB wpk + 8KB red = 72KB -> 2 blocks/CU retained.
__global__ __launch_bounds__(256) void gemm_fused(
    const float* __restrict__ hs, const float* __restrict__ seqW,
    const float* __restrict__ hidW, const float* __restrict__ cpw,
    unsigned short* __restrict__ E16 /* [2][4096][32] bf16 */)
{
    __shared__ short wpk[32768];     // 4096 fragments x 16B = 64 KB
    __shared__ float red[4][16][32]; // 8 KB

    const int bid = blockIdx.x;
    const bool hid = bid >= 256;
    const int mt  = hid ? bid - 256 : bid;
    const int tid = threadIdx.x;
    const int wv  = tid >> 6;
    const int l   = tid & 63;
    const int l15 = l & 15;
    const int g   = l >> 4;
    const int m0  = mt * 16;
    const int mrow = m0 + l15;

    const float* __restrict__ W = hid ? hidW : seqW;

    // ---- stage W (32 rows x 1024 k fp32) -> LDS bf16 fragments, coalesced ----
    {
        const int kstep = tid >> 3;        // 0..31
        const int gg    = (tid >> 1) & 3;  // 0..3
        const int half  = tid & 1;         // k-offset 0 or 4 within fragment
        #pragma unroll 4
        for (int row = 0; row < 32; ++row) {
            f32x4 v = *(const f32x4*)(W + (size_t)row * 1024 + tid * 4);
            short4v h4 = { (short)f2bf(v.x), (short)f2bf(v.y),
                           (short)f2bf(v.z), (short)f2bf(v.w) };
            const int frag = (row >> 4) * 2048 + kstep * 64 + gg * 16 + (row & 15);
            *(short4v*)&wpk[frag * 8 + half * 4] = h4;
        }
    }

    size_t arow;
    if (hid) arow = ((size_t)(mrow >> 10) << 20) + (size_t)(mrow & 1023);
    else     arow = (size_t)mrow << 10;

    __syncthreads();

    f32x4 acc0 = {0.f,0.f,0.f,0.f}, acc1 = {0.f,0.f,0.f,0.f};
    const int kbase = wv * 256;

    #pragma unroll
    for (int ks = 0; ks < 8; ++ks) {
        const int kb = kbase + ks * 32 + g * 8;
        const int kstep = wv * 8 + ks;
        bf16x8 af, bf0, bf1;
        if (hid) {
            const float* pa = hs + arow + (size_t)kb * 1024;
            float a[8];
            #pragma unroll
            for (int j = 0; j < 8; ++j) a[j] = pa[(size_t)j * 1024];
            #pragma unroll
            for (int j = 0; j < 8; ++j) af[j] = (short)f2bf(a[j]);
        } else {
            const f32x4* pa = (const f32x4*)(hs + arow + kb);
            f32x4 a0 = pa[0], a1 = pa[1];
            af[0]=(short)f2bf(a0.x); af[1]=(short)f2bf(a0.y); af[2]=(short)f2bf(a0.z); af[3]=(short)f2bf(a0.w);
            af[4]=(short)f2bf(a1.x); af[5]=(short)f2bf(a1.y); af[6]=(short)f2bf(a1.z); af[7]=(short)f2bf(a1.w);
        }
        bf0 = *(const bf16x8*)&wpk[(kstep * 64 + g * 16 + l15) * 8];
        bf1 = *(const bf16x8*)&wpk[(2048 + kstep * 64 + g * 16 + l15) * 8];
        acc0 = __builtin_amdgcn_mfma_f32_16x16x32_bf16(af, bf0, acc0, 0, 0, 0);
        acc1 = __builtin_amdgcn_mfma_f32_16x16x32_bf16(af, bf1, acc1, 0, 0, 0);
    }

    // C/D layout (m89-verified): col = lane&15, row = (lane>>4)*4 + reg
    #pragma unroll
    for (int r = 0; r < 4; ++r) {
        red[wv][4 * g + r][l15]      = acc0[r];
        red[wv][4 * g + r][l15 + 16] = acc1[r];
    }
    __syncthreads();

    // Sum 4 wave-partials -> fold cpw (seq only) -> bf16 pack -> 4B store.
    const int o = tid * 2;
    const float* rf = &red[0][0][0];
    float vx = rf[o]     + rf[512 + o]     + rf[1024 + o]     + rf[1536 + o];
    float vy = rf[o + 1] + rf[512 + o + 1] + rf[1024 + o + 1] + rf[1536 + o + 1];
    if (!hid) {
        f32x2 w = *(const f32x2*)(cpw + (o & 31));
        vx *= w.x; vy *= w.y;
    }
    unsigned pk = (unsigned)f2bf(vx) | ((unsigned)f2bf(vy) << 16);
    unsigned short* Eo = E16 + (hid ? (size_t)4096 * 32 : 0) + (size_t)m0 * 32 + o;
    *(unsigned*)Eo = pk;
}

// K3: rank-32 GEMM via MFMA (R14 verbatim, nt stores). Measured ~3-4us.
__global__ __launch_bounds__(256) void k3(const unsigned short* __restrict__ E16,
                                          float* __restrict__ out)
{
    const int tid = threadIdx.x;
    const int wv  = tid >> 6;
    const int l   = tid & 63;
    const int l15 = l & 15;
    const int g   = l >> 4;
    const int b   = blockIdx.z;
    const int s0  = blockIdx.y * 64 + wv * 16;
    const int h0  = blockIdx.x * 64;

    const unsigned short* As = E16 + ((size_t)(b * 1024 + s0)) * 32;
    const unsigned short* Bh = E16 + (size_t)4096 * 32 + ((size_t)(b * 1024 + h0)) * 32;

    bf16x8 af = *(const bf16x8*)(As + (size_t)l15 * 32 + g * 8);
    bf16x8 bfr[4];
    #pragma unroll
    for (int j = 0; j < 4; ++j)
        bfr[j] = *(const bf16x8*)(Bh + (size_t)(4 * l15 + j) * 32 + g * 8);

    const f32x4 zero = {0.f, 0.f, 0.f, 0.f};
    f32x4 acc[4];
    #pragma unroll
    for (int j = 0; j < 4; ++j)
        acc[j] = __builtin_amdgcn_mfma_f32_16x16x32_bf16(af, bfr[j], zero, 0, 0, 0);

    #pragma unroll
    for (int r = 0; r < 4; ++r) {
        f32x4 v = { acc[0][r], acc[1][r], acc[2][r], acc[3][r] };
        float* orow = out + ((size_t)(b * 1024 + s0 + 4 * g + r)) * 1024 + h0 + 4 * l15;
        __builtin_nontemporal_store(v, (f32x4*)orow);
    }
}

extern "C" void kernel_launch(void* const* d_in, const int* in_sizes, int n_in,
                              void* d_out, int out_size, void* d_ws, size_t ws_size,
                              hipStream_t stream) {
    const float* hs   = (const float*)d_in[0];
    // d_in[1] = all_indices: identically (n/H, n%H) -> computed implicitly
    const float* seqW = (const float*)d_in[2];
    const float* hidW = (const float*)d_in[3];
    const float* cpw  = (const float*)d_in[4];
    float* out = (float*)d_out;

    unsigned short* E16 = (unsigned short*)d_ws;   // [2][4096][32] bf16, 512 KB

    gemm_fused<<<512, 256, 0, stream>>>(hs, seqW, hidW, cpw, E16);
    dim3 grid3(16, 16, 4);
    k3<<<grid3, 256, 0, stream>>>(E16, out);
}

// Round 17
// 20.770 us; speedup vs baseline: 1.2906x; 1.0227x over previous
//
#include <hip/hip_runtime.h>

typedef __attribute__((ext_vector_type(8))) short bf16x8;
typedef __attribute__((ext_vector_type(4))) float f32x4;
typedef __attribute__((ext_vector_type(2))) float f32x2;
typedef __attribute__((ext_vector_type(4))) short short4v;

// Native cast -> v_cvt_pk_bf16_f32 on gfx950 (RNE).
__device__ __forceinline__ unsigned short f2bf(float x) {
    union { __bf16 h; unsigned short s; } u;
    u.h = (__bf16)x;
    return u.s;
}

// K1: fused skinny GEMMs. R17 change: MLP restructure (issue-early/use-late).
// Evidence: gemm ~10us with all data cache-resident across R3..R16 while every
// BW/coalescing fix was neutral; R12 rocprof showed VGPR_Count=28 -> compiler
// keeps ~2 loads in flight -> 8 iters x L2-latency paid serially. Fix: load the
// wave's ENTIRE A-slice (64 floats) into a statically-indexed register array
// before the barrier; staging work + barrier hide the one-shot latency; the
// MFMA loop then runs with zero global accesses. Numerics bit-identical.
// LDS: 64KB wpk (W in MFMA-fragment bf16 layout, R16) + 8KB red.
__global__ __launch_bounds__(256) void gemm_fused(
    const float* __restrict__ hs, const float* __restrict__ seqW,
    const float* __restrict__ hidW, const float* __restrict__ cpw,
    unsigned short* __restrict__ E16 /* [2][4096][32] bf16 */)
{
    __shared__ short wpk[32768];     // 4096 fragments x 16B = 64 KB
    __shared__ float red[4][16][32]; // 8 KB

    const int bid = blockIdx.x;
    const bool hid = bid >= 256;
    const int mt  = hid ? bid - 256 : bid;
    const int tid = threadIdx.x;
    const int wv  = tid >> 6;
    const int l   = tid & 63;
    const int l15 = l & 15;
    const int g   = l >> 4;
    const int m0  = mt * 16;
    const int mrow = m0 + l15;

    const float* __restrict__ W = hid ? hidW : seqW;
    size_t arow;
    if (hid) arow = ((size_t)(mrow >> 10) << 20) + (size_t)(mrow & 1023);
    else     arow = (size_t)mrow << 10;
    const int kbase = wv * 256;

    // ---- stage W (32 rows x 1024 k fp32) -> LDS bf16 fragments (R16) ----
    {
        const int kstep = tid >> 3;        // 0..31
        const int gg    = (tid >> 1) & 3;  // 0..3
        const int half  = tid & 1;         // k-offset 0 or 4 within fragment
        #pragma unroll 4
        for (int row = 0; row < 32; ++row) {
            f32x4 v = *(const f32x4*)(W + (size_t)row * 1024 + tid * 4);
            short4v h4 = { (short)f2bf(v.x), (short)f2bf(v.y),
                           (short)f2bf(v.z), (short)f2bf(v.w) };
            const int frag = (row >> 4) * 2048 + kstep * 64 + gg * 16 + (row & 15);
            *(short4v*)&wpk[frag * 8 + half * 4] = h4;
        }
    }

    // ---- issue the wave's ENTIRE A-slice into registers (64 floats/lane) ----
    // Static indexing only (fully unrolled) -> stays in VGPRs, all loads
    // issued back-to-back; __syncthreads' vmcnt(0) drain lands them while the
    // staging above is still completing. One latency exposure, not 8.
    float a[64];
    if (hid) {
        const float* pa = hs + arow + (size_t)(kbase + g * 8) * 1024;
        #pragma unroll
        for (int ks = 0; ks < 8; ++ks)
            #pragma unroll
            for (int j = 0; j < 8; ++j)
                a[ks * 8 + j] = pa[(size_t)(ks * 32 + j) * 1024];
    } else {
        const f32x4* pa = (const f32x4*)(hs + arow + kbase + g * 8);
        #pragma unroll
        for (int ks = 0; ks < 8; ++ks) {
            f32x4 v0 = pa[ks * 8];       // k = kbase + ks*32 + g*8 .. +4
            f32x4 v1 = pa[ks * 8 + 1];   // .. +4..+8
            a[ks*8+0]=v0.x; a[ks*8+1]=v0.y; a[ks*8+2]=v0.z; a[ks*8+3]=v0.w;
            a[ks*8+4]=v1.x; a[ks*8+5]=v1.y; a[ks*8+6]=v1.z; a[ks*8+7]=v1.w;
        }
    }

    __syncthreads();

    // ---- MFMA loop: pure register cvt + LDS B-reads, zero global accesses ----
    f32x4 acc0 = {0.f,0.f,0.f,0.f}, acc1 = {0.f,0.f,0.f,0.f};
    #pragma unroll
    for (int ks = 0; ks < 8; ++ks) {
        const int kstep = wv * 8 + ks;
        bf16x8 af, bf0, bf1;
        #pragma unroll
        for (int j = 0; j < 8; ++j) af[j] = (short)f2bf(a[ks * 8 + j]);
        bf0 = *(const bf16x8*)&wpk[(kstep * 64 + g * 16 + l15) * 8];
        bf1 = *(const bf16x8*)&wpk[(2048 + kstep * 64 + g * 16 + l15) * 8];
        acc0 = __builtin_amdgcn_mfma_f32_16x16x32_bf16(af, bf0, acc0, 0, 0, 0);
        acc1 = __builtin_amdgcn_mfma_f32_16x16x32_bf16(af, bf1, acc1, 0, 0, 0);
    }

    // C/D layout (m89-verified): col = lane&15, row = (lane>>4)*4 + reg
    #pragma unroll
    for (int r = 0; r < 4; ++r) {
        red[wv][4 * g + r][l15]      = acc0[r];
        red[wv][4 * g + r][l15 + 16] = acc1[r];
    }
    __syncthreads();

    // Sum 4 wave-partials -> fold cpw (seq only) -> bf16 pack -> 4B store.
    const int o = tid * 2;
    const float* rf = &red[0][0][0];
    float vx = rf[o]     + rf[512 + o]     + rf[1024 + o]     + rf[1536 + o];
    float vy = rf[o + 1] + rf[512 + o + 1] + rf[1024 + o + 1] + rf[1536 + o + 1];
    if (!hid) {
        f32x2 w = *(const f32x2*)(cpw + (o & 31));
        vx *= w.x; vy *= w.y;
    }
    unsigned pk = (unsigned)f2bf(vx) | ((unsigned)f2bf(vy) << 16);
    unsigned short* Eo = E16 + (hid ? (size_t)4096 * 32 : 0) + (size_t)m0 * 32 + o;
    *(unsigned*)Eo = pk;
}

// K3: rank-32 GEMM via MFMA (R14 verbatim, nt stores). Measured ~3.5us.
__global__ __launch_bounds__(256) void k3(const unsigned short* __restrict__ E16,
                                          float* __restrict__ out)
{
    const int tid = threadIdx.x;
    const int wv  = tid >> 6;
    const int l   = tid & 63;
    const int l15 = l & 15;
    const int g   = l >> 4;
    const int b   = blockIdx.z;
    const int s0  = blockIdx.y * 64 + wv * 16;
    const int h0  = blockIdx.x * 64;

    const unsigned short* As = E16 + ((size_t)(b * 1024 + s0)) * 32;
    const unsigned short* Bh = E16 + (size_t)4096 * 32 + ((size_t)(b * 1024 + h0)) * 32;

    bf16x8 af = *(const bf16x8*)(As + (size_t)l15 * 32 + g * 8);
    bf16x8 bfr[4];
    #pragma unroll
    for (int j = 0; j < 4; ++j)
        bfr[j] = *(const bf16x8*)(Bh + (size_t)(4 * l15 + j) * 32 + g * 8);

    const f32x4 zero = {0.f, 0.f, 0.f, 0.f};
    f32x4 acc[4];
    #pragma unroll
    for (int j = 0; j < 4; ++j)
        acc[j] = __builtin_amdgcn_mfma_f32_16x16x32_bf16(af, bfr[j], zero, 0, 0, 0);

    #pragma unroll
    for (int r = 0; r < 4; ++r) {
        f32x4 v = { acc[0][r], acc[1][r], acc[2][r], acc[3][r] };
        float* orow = out + ((size_t)(b * 1024 + s0 + 4 * g + r)) * 1024 + h0 + 4 * l15;
        __builtin_nontemporal_store(v, (f32x4*)orow);
    }
}

extern "C" void kernel_launch(void* const* d_in, const int* in_sizes, int n_in,
                              void* d_out, int out_size, void* d_ws, size_t ws_size,
                              hipStream_t stream) {
    const float* hs   = (const float*)d_in[0];
    // d_in[1] = all_indices: identically (n/H, n%H) -> computed implicitly
    const float* seqW = (const float*)d_in[2];
    const float* hidW = (const float*)d_in[3];
    const float* cpw  = (const float*)d_in[4];
    float* out = (float*)d_out;

    unsigned short* E16 = (unsigned short*)d_ws;   // [2][4096][32] bf16, 512 KB

    gemm_fused<<<512, 256, 0, stream>>>(hs, seqW, hidW, cpw, E16);
    dim3 grid3(16, 16, 4);
    k3<<<grid3, 256, 0, stream>>>(E16, out);
}